// Round 12
// baseline (245.940 us; speedup 1.0000x reference)
//
#include <hip/hip_runtime.h>

#define H 512
#define NTOK 64
#define NPIX 49
#define CDIM 2048
#define VOCAB 10000

// ws layout (float offsets). NO region requires zero-init (all plain-stored).
#define WS_S      0         // 64x512
#define WS_FM     163840    // 8x2048
#define WS_G2F    180224    // 64x512 reduced G2
#define WS_P1     212992    // 8 kc x 64 n x 64  (h@Wg partials)
#define WS_P2     245760    // 8 kc x 64 n x 64  (s@Ws partials)
#define WS_CCH    278528    // 16 kc x 64 n x 52 (cchan partials)
#define WS_A0     331776    // 64x2048 RAW cxt; CHT bf16 alias after death
#define WS_CHT    331776    // chat bf16 [n][512] (shorts)
// disjoint slab regions (ws is ~268MB; no time-sharing needed)
#define WS_SG2S   462848    // 48 x 32768  sg2 slabs (st*16+kc)
#define WS_GSPS   2035712   // 64 x 32768  gates+spat slabs (st*8+kc)
#define WS_MS     4132864   // 16 x 153664 M partial slabs
#define WS_MF     9151488   // 64 x 2401 reduced M
// end = 9305152 floats ~= 37.2 MB

#define OUT_ALPHA 640000
#define OUT_BETA  643136

typedef __attribute__((ext_vector_type(8))) short short8;
typedef __attribute__((ext_vector_type(4))) float floatx4;

__device__ __forceinline__ float rcp_fast(float x) {
#if __has_builtin(__builtin_amdgcn_rcpf)
  return __builtin_amdgcn_rcpf(x);
#else
  return 1.0f / x;
#endif
}
__device__ __forceinline__ float tanh_f(float x) {
  float e = __expf(2.0f * x);
  return 1.0f - 2.0f * rcp_fast(e + 1.0f);
}
__device__ __forceinline__ float sigmoid_f(float x) {
  return rcp_fast(1.0f + __expf(-x));
}
__device__ __forceinline__ short f2bf(float x) {  // RNE fp32->bf16
  union { float f; unsigned u; } un; un.f = x;
  unsigned r = un.u + 0x7FFFu + ((un.u >> 16) & 1u);
  return (short)(r >> 16);
}
__device__ __forceinline__ float bf2f(unsigned short h) {
  union { unsigned u; float f; } cv; cv.u = ((unsigned)h) << 16;
  return cv.f;
}

// sg2 + featmean. bid<384: gemm streams 0:(x,Wsx) 1:(hprev,Wsh) 2:(h,Wg2)
// with self-staged A chunk; bid>=384: featmean.
__global__ __launch_bounds__(256) void k_sg2(const float* __restrict__ Wsx,
    const float* __restrict__ Wsh, const float* __restrict__ Wg2,
    const float* __restrict__ x, const float* __restrict__ hid,
    const float* __restrict__ V, float* __restrict__ ws) {
  int bid = blockIdx.x, tid = threadIdx.x;
  if (bid < 384) {
    __shared__ float aT[32 * 20];
    int c2 = bid & 1, kc = (bid >> 1) & 15, z = bid >> 5;   // z 0..11
    int st = z >> 2, n0 = (z & 3) * 16;
    int c = c2 * 256 + tid;
    int k0 = kc * 32;
    const float* W = (st == 0) ? Wsx : (st == 1) ? Wsh : Wg2;
    for (int i = tid; i < 512; i += 256) {
      int nn = i >> 5, kk = i & 31;
      int tok = n0 + nn;
      float v;
      if (st == 0)      v = x[tok * 512 + k0 + kk];
      else if (st == 1) v = (tok & 7) ? hid[(tok - 1) * 512 + k0 + kk] : 0.0f;
      else              v = hid[tok * 512 + k0 + kk];
      aT[kk * 20 + nn] = v;
    }
    __syncthreads();
    float acc[16];
#pragma unroll
    for (int j = 0; j < 16; ++j) acc[j] = 0.0f;
#pragma unroll 4
    for (int kk = 0; kk < 32; ++kk) {
      float w = W[(k0 + kk) * 512 + c];
      const float4* a4 = (const float4*)&aT[kk * 20];
#pragma unroll
      for (int q = 0; q < 4; ++q) {
        float4 a = a4[q];
        acc[q * 4 + 0] += a.x * w;
        acc[q * 4 + 1] += a.y * w;
        acc[q * 4 + 2] += a.z * w;
        acc[q * 4 + 3] += a.w * w;
      }
    }
    float* C = ws + WS_SG2S + (st * 16 + kc) * 32768;
#pragma unroll
    for (int j = 0; j < 16; ++j) C[(n0 + j) * 512 + c] = acc[j];
  } else {
    int fb = bid - 384;
    int b = fb >> 3, c = (fb & 7) * 256 + tid;
    float s = 0.0f;
    for (int k = 0; k < NPIX; ++k) s += V[b * NPIX * CDIM + k * CDIM + c];
    ws[WS_FM + b * CDIM + c] = s * (1.0f / NPIX);
  }
}

// reduce slabs: S = sigmoid(sum slabs 0..31)*tanh(cells) -> S ; G2F = sum slabs 32..47
__global__ __launch_bounds__(256) void k_act_s(const float* __restrict__ cells,
    float* __restrict__ ws) {
  int idx = blockIdx.x * 256 + threadIdx.x;
  float sa = 0.0f, g = 0.0f;
#pragma unroll
  for (int s = 0; s < 32; ++s) sa += ws[WS_SG2S + s * 32768 + idx];
#pragma unroll
  for (int s = 32; s < 48; ++s) g += ws[WS_SG2S + s * 32768 + idx];
  ws[WS_S + idx] = sigmoid_f(sa) * tanh_f(cells[idx]);
  ws[WS_G2F + idx] = g;
}

// bid<512: cxt raw ; 512<=bid<768: gates GEMMs (self-staged) ; bid>=768: cs_hwg
__global__ __launch_bounds__(256) void k_mid(const float* __restrict__ Wfeat,
    const float* __restrict__ Wcxt, const float* __restrict__ Wgvs,
    const float* __restrict__ Wghs, const float* __restrict__ Wgvc,
    const float* __restrict__ Wghc, const float* __restrict__ hid,
    const float* __restrict__ Wg, const float* __restrict__ Ws_,
    float* __restrict__ ws) {
  int bid = blockIdx.x, tid = threadIdx.x;
  if (bid < 512) {
    __shared__ float2 fw[512];
    __shared__ float g2l[512];
    int n = bid & 63, b = n >> 3;
    int c = (bid >> 6) * 256 + tid;
    for (int i = tid; i < 512; i += 256) {
      fw[i] = make_float2(Wfeat[i], Wcxt[i]);
      g2l[i] = ws[WS_G2F + n * H + i];
    }
    __syncthreads();
    float fm = ws[WS_FM + b * CDIM + c];
    float acc = 0.0f;
#pragma unroll 4
    for (int j = 0; j < 512; ++j) {
      float2 p = fw[j];
      acc += tanh_f(fm * p.x + g2l[j]) * p.y;
    }
    ws[WS_A0 + n * CDIM + c] = acc;
  } else if (bid < 768) {
    __shared__ float aT[64 * 20];
    int gi = bid - 512;                 // 0..255
    int c = (gi & 1) * 256 + tid;
    int rest = gi >> 1;                 // 0..127
    int kc = rest & 7;
    int zz = rest >> 3;                 // 0..15
    int st = zz >> 2, n0 = (zz & 3) * 16;
    int k0 = kc * 64;
    const float* Asrc = (st & 1) ? hid : (ws + WS_S);
    const float* W = (st == 0) ? Wgvs : (st == 1) ? Wghs : (st == 2) ? Wgvc : Wghc;
    for (int i = tid; i < 1024; i += 256) {
      int nn = i >> 6, kk = i & 63;
      aT[kk * 20 + nn] = Asrc[(n0 + nn) * 512 + k0 + kk];
    }
    __syncthreads();
    float acc[16];
#pragma unroll
    for (int j = 0; j < 16; ++j) acc[j] = 0.0f;
#pragma unroll 4
    for (int kk = 0; kk < 64; ++kk) {
      float w = W[(k0 + kk) * 512 + c];
      const float4* a4 = (const float4*)&aT[kk * 20];
#pragma unroll
      for (int q = 0; q < 4; ++q) {
        float4 a = a4[q];
        acc[q * 4 + 0] += a.x * w;
        acc[q * 4 + 1] += a.y * w;
        acc[q * 4 + 2] += a.z * w;
        acc[q * 4 + 3] += a.w * w;
      }
    }
    float* C = ws + WS_GSPS + (st * 8 + kc) * 32768;
#pragma unroll
    for (int j = 0; j < 16; ++j) C[(n0 + j) * 512 + c] = acc[j];
  } else {
    int bidx = bid - 768;               // 0..127
    int n = bidx & 63, half = bidx >> 6;
    int k2 = tid & 63, w = tid >> 6;
    int kc = half * 4 + w;
    const float* hrow = hid + n * H;
    const float* srow = ws + WS_S + n * H;
    float a1 = 0.0f, a2 = 0.0f;
#pragma unroll 4
    for (int kk = 0; kk < 64; ++kk) {
      int k = kc * 64 + kk;
      if (k2 < NPIX) {
        a1 += hrow[k] * Wg[k * NPIX + k2];
        a2 += srow[k] * Ws_[k * NPIX + k2];
      }
    }
    if (k2 < NPIX) {
      ws[WS_P1 + (kc * 64 + n) * 64 + k2] = a1;
      ws[WS_P2 + (kc * 64 + n) * 64 + k2] = a2;
    }
  }
}

// attnM via bf16 MFMA, softmax fused. grid 1024 = (16 kc)x(64 n).
__global__ __launch_bounds__(256) void k_attnM(const float* __restrict__ V,
    const float* __restrict__ Wv, float* __restrict__ ws) {
  __shared__ __align__(16) short al[64 * 136];
  __shared__ __align__(16) short bl[64 * 136];
  __shared__ float red[8];
  int tid = threadIdx.x, bid = blockIdx.x;
  int kc = bid >> 6, n = bid & 63, b = n >> 3;
  int c0 = kc * 128;
  const float* cr = ws + WS_A0 + n * CDIM;
  const float* Vb = V + b * NPIX * CDIM + c0;
  int lane = tid & 63, w = tid >> 6;
  float v[8];
  float vmax = -1e30f;
#pragma unroll
  for (int i = 0; i < 8; ++i) { v[i] = cr[tid + i * 256]; vmax = fmaxf(vmax, v[i]); }
  for (int off = 32; off; off >>= 1) vmax = fmaxf(vmax, __shfl_xor(vmax, off));
  if (lane == 0) red[w] = vmax;
  __syncthreads();
  float m = fmaxf(fmaxf(red[0], red[1]), fmaxf(red[2], red[3]));
  float ss = 0.0f;
#pragma unroll
  for (int i = 0; i < 8; ++i) ss += __expf(v[i] - m);
  for (int off = 32; off; off >>= 1) ss += __shfl_xor(ss, off);
  if (lane == 0) red[4 + w] = ss;
  __syncthreads();
  float inv = rcp_fast(red[4] + red[5] + red[6] + red[7]);
  {
    int cc = tid & 127;
    float a0c = __expf(cr[c0 + cc] - m) * inv;
    for (int k = tid >> 7; k < NPIX; k += 2)
      al[k * 136 + cc] = f2bf(a0c * Vb[k * CDIM + cc]);
  }
  for (int idx = tid; idx < 128 * 64; idx += 256) {
    int cc = idx >> 6, r = idx & 63;
    if (r < NPIX) bl[r * 136 + cc] = f2bf(Wv[(c0 + cc) * NPIX + r]);
  }
  __syncthreads();
  if (tid < NPIX) {
    float cch = 0.0f;
    const unsigned short* ar = (const unsigned short*)(al + tid * 136);
#pragma unroll 8
    for (int cc = 0; cc < 128; ++cc) cch += bf2f(ar[cc]);
    ws[WS_CCH + (kc * 64 + n) * 52 + tid] = cch * (1.0f / CDIM);
  }
  int qm = lane >> 4, mr = lane & 15;
  floatx4 acc[4];
#pragma unroll
  for (int i = 0; i < 4; ++i) acc[i] = (floatx4){0.f, 0.f, 0.f, 0.f};
#pragma unroll
  for (int ks = 0; ks < 4; ++ks) {
    int cb = ks * 32 + qm * 8;
    short8 bf = *(const short8*)&bl[(w * 16 + mr) * 136 + cb];
#pragma unroll
    for (int i = 0; i < 4; ++i) {
      short8 af = *(const short8*)&al[(i * 16 + mr) * 136 + cb];
      acc[i] = __builtin_amdgcn_mfma_f32_16x16x32_bf16(af, bf, acc[i], 0, 0, 0);
    }
  }
  __syncthreads();
  float* ml = (float*)al;
  int k2 = w * 16 + mr;
  if (k2 < NPIX) {
#pragma unroll
    for (int i = 0; i < 4; ++i) {
#pragma unroll
      for (int r = 0; r < 4; ++r) {
        int kp = i * 16 + qm * 4 + r;
        if (kp < NPIX) ml[k2 * 49 + kp] = acc[i][r];
      }
    }
  }
  __syncthreads();
  float* Mp = ws + WS_MS + kc * 153664 + n * 2401;
  for (int idx = tid; idx < 2401; idx += 256) Mp[idx] = ml[idx];
}

// reduce the 16 M slabs -> MF[n][2401] ; grid (10, 64)
__global__ __launch_bounds__(256) void k_redM(float* __restrict__ ws) {
  int n = blockIdx.y;
  int i = blockIdx.x * 256 + threadIdx.x;
  if (i < 2401) {
    float m = 0.0f;
#pragma unroll
    for (int s = 0; s < 16; ++s) m += ws[WS_MS + s * 153664 + n * 2401 + i];
    ws[WS_MF + n * 2401 + i] = m;
  }
}

// zt: reduce P1/P2; z from single MF slab; alpha, beta
__global__ __launch_bounds__(256) void k_zt(const float* __restrict__ Wh,
    float* __restrict__ ws, float* __restrict__ out) {
  __shared__ float gl[NPIX], cl[NPIX], whl[64];
  __shared__ float zbuf[4][64];
  int n = blockIdx.x, tid = threadIdx.x;
  if (tid < NPIX) {
    float s1 = 0.0f, s2 = 0.0f;
#pragma unroll
    for (int kc = 0; kc < 8; ++kc) {
      s1 += ws[WS_P1 + (kc * 64 + n) * 64 + tid];
      s2 += ws[WS_P2 + (kc * 64 + n) * 64 + tid];
    }
    gl[tid] = s1;
    cl[tid] = s1 + s2;
    whl[tid] = Wh[tid];
  }
  __syncthreads();
  int k = tid & 63, g = tid >> 6;
  float zp = 0.0f;
  if (k < NPIX) {
    int k2e = (g == 3) ? NPIX : (g * 13 + 13);
    const float* Mz = ws + WS_MF + n * 2401;
    for (int k2 = g * 13; k2 < k2e; ++k2) {
      float m = Mz[k2 * 49 + k];
      zp += tanh_f(tanh_f(m + gl[k2])) * whl[k2];
    }
  }
  zbuf[g][k] = zp;
  __syncthreads();
  if (tid < 64) {
    int lane = tid;
    float z = zbuf[0][lane] + zbuf[1][lane] + zbuf[2][lane] + zbuf[3][lane];
    float zm = (lane < NPIX) ? z : -1e30f;
    float m1 = zm;
    for (int off = 32; off; off >>= 1) m1 = fmaxf(m1, __shfl_xor(m1, off));
    float e = (lane < NPIX) ? __expf(z - m1) : 0.0f;
    float S1 = e;
    for (int off = 32; off; off >>= 1) S1 += __shfl_xor(S1, off);
    if (lane < NPIX) out[OUT_ALPHA + n * NPIX + lane] = e * rcp_fast(S1);
    float vz = (lane < NPIX) ? tanh_f(cl[lane]) * whl[lane] : 0.0f;
    for (int off = 32; off; off >>= 1) vz += __shfl_xor(vz, off);
    if (lane == 0) {
      float ze = vz;
      float m2 = fmaxf(m1, ze);
      float S2 = S1 * __expf(m1 - m2) + __expf(ze - m2);
      out[OUT_BETA + n] = __expf(ze - m2) * rcp_fast(S2);
    }
  }
}

// FUSED c_spatial + spat gemm. grid (2 c2, 8 kc, 16 z={q*4+n0g}).
// Phase A: compute A[d][n] = sum_kp alpha[n][kp] * V[b(n)][kp][d0+d] in LDS.
// Phase B: GSPS slab [(4+q)*8+kc] rows n0..n0+16 = A^T chunk @ Wspat rows d0..d0+64.
__global__ __launch_bounds__(256) void k_cspat(const float* __restrict__ V,
    const float* __restrict__ Wspat, const float* __restrict__ out,
    float* __restrict__ ws) {
  __shared__ float vs[2 * 49 * 64];   // 25 KB
  __shared__ float alp[16 * 64];      // 4 KB
  __shared__ float aT[64 * 20];       // 5 KB
  int tid = threadIdx.x;
  int c2 = blockIdx.x, kc = blockIdx.y, z = blockIdx.z;
  int q = z >> 2, n0 = (z & 3) * 16;
  int d0 = q * 512 + kc * 64;
  int b0 = n0 >> 3;                   // spans batches b0, b0+1
  for (int i = tid; i < 2 * 49 * 64; i += 256) {
    int d = i & 63, t = i >> 6;       // t 0..97
    int bb = (t >= 49) ? 1 : 0;
    int kp = t - bb * 49;
    vs[i] = V[(b0 + bb) * NPIX * CDIM + kp * CDIM + d0 + d];
  }
  for (int i = tid; i < 1024; i += 256) {
    int nl = i >> 6, kp = i & 63;
    alp[i] = (kp < NPIX) ? out[OUT_ALPHA + (n0 + nl) * NPIX + kp] : 0.0f;
  }
  __syncthreads();
  {
    int d = tid & 63, ng = tid >> 6;  // ng wave-uniform
    int bb = ng >> 1;
    float a0 = 0.f, a1 = 0.f, a2 = 0.f, a3 = 0.f;
#pragma unroll 7
    for (int kp = 0; kp < NPIX; ++kp) {
      float v = vs[(bb * 49 + kp) * 64 + d];
      a0 += alp[(ng * 4 + 0) * 64 + kp] * v;
      a1 += alp[(ng * 4 + 1) * 64 + kp] * v;
      a2 += alp[(ng * 4 + 2) * 64 + kp] * v;
      a3 += alp[(ng * 4 + 3) * 64 + kp] * v;
    }
    aT[d * 20 + ng * 4 + 0] = a0;
    aT[d * 20 + ng * 4 + 1] = a1;
    aT[d * 20 + ng * 4 + 2] = a2;
    aT[d * 20 + ng * 4 + 3] = a3;
  }
  __syncthreads();
  int c = c2 * 256 + tid;
  float acc[16];
#pragma unroll
  for (int j = 0; j < 16; ++j) acc[j] = 0.0f;
#pragma unroll 4
  for (int kk = 0; kk < 64; ++kk) {
    float w = Wspat[(d0 + kk) * 512 + c];
    const float4* a4 = (const float4*)&aT[kk * 20];
#pragma unroll
    for (int q2 = 0; q2 < 4; ++q2) {
      float4 a = a4[q2];
      acc[q2 * 4 + 0] += a.x * w;
      acc[q2 * 4 + 1] += a.y * w;
      acc[q2 * 4 + 2] += a.z * w;
      acc[q2 * 4 + 3] += a.w * w;
    }
  }
  float* C = ws + WS_GSPS + ((4 + q) * 8 + kc) * 32768;
#pragma unroll
  for (int j = 0; j < 16; ++j) C[(n0 + j) * 512 + c] = acc[j];
}

// chat[n][c] = sigmoid(GA1)*SPAT + sigmoid(GA2)*(cchan@Wchan) + h -> bf16 [n][512]
__global__ __launch_bounds__(256) void k_chat(const float* __restrict__ hid,
    const float* __restrict__ Wchan, float* __restrict__ ws) {
  __shared__ float cl[NPIX];
  int tid = threadIdx.x, n = blockIdx.y;
  int c = blockIdx.x * 256 + tid;
  if (tid < NPIX) {
    float s = 0.0f;
#pragma unroll
    for (int kc = 0; kc < 16; ++kc) s += ws[WS_CCH + (kc * 64 + n) * 52 + tid];
    cl[tid] = s;
  }
  __syncthreads();
  float acc = 0.0f;
#pragma unroll 7
  for (int k = 0; k < NPIX; ++k) acc += cl[k] * Wchan[k * H + c];
  int idx = n * H + c;
  float ga1 = 0.0f, ga2 = 0.0f, spat = 0.0f;
#pragma unroll
  for (int s = 0; s < 16; ++s)  ga1 += ws[WS_GSPS + s * 32768 + idx];
#pragma unroll
  for (int s = 16; s < 32; ++s) ga2 += ws[WS_GSPS + s * 32768 + idx];
#pragma unroll
  for (int s = 32; s < 64; ++s) spat += ws[WS_GSPS + s * 32768 + idx];
  float chat = sigmoid_f(ga1) * spat + sigmoid_f(ga2) * acc + hid[idx];
  ((short*)(ws + WS_CHT))[idx] = f2bf(chat);
}

// scores via bf16 MFMA, single pass K=512, writes out with bias. grid (157).
__global__ __launch_bounds__(256) void k_gemm_scores(const float* __restrict__ Wmlp,
    const float* __restrict__ bmlp, float* __restrict__ ws,
    float* __restrict__ out) {
  __shared__ __align__(16) short bl[64 * 136];
  int tid = threadIdx.x;
  int cb = blockIdx.x;
  int c0 = cb * 64;
  const short* CHB = (const short*)(ws + WS_CHT);
  int lane = tid & 63, w = tid >> 6;
  int mr = lane & 15, kg = lane >> 4;
  floatx4 acc[4];
#pragma unroll
  for (int i = 0; i < 4; ++i) acc[i] = (floatx4){0.f, 0.f, 0.f, 0.f};
#pragma unroll
  for (int s = 0; s < 4; ++s) {
    int k0 = s * 128;
    __syncthreads();
    for (int i = tid; i < 128 * 64; i += 256) {
      int kk = i >> 6, cc = i & 63;
      int c = c0 + cc;
      float v = (c < VOCAB) ? Wmlp[(k0 + kk) * VOCAB + c] : 0.0f;
      bl[cc * 136 + kk] = f2bf(v);
    }
    __syncthreads();
#pragma unroll
    for (int ks = 0; ks < 4; ++ks) {
      short8 af = *(const short8*)&CHB[(w * 16 + mr) * 512 + k0 + ks * 32 + kg * 8];
#pragma unroll
      for (int ct = 0; ct < 4; ++ct) {
        short8 bf = *(const short8*)&bl[(ct * 16 + mr) * 136 + ks * 32 + kg * 8];
        acc[ct] = __builtin_amdgcn_mfma_f32_16x16x32_bf16(af, bf, acc[ct], 0, 0, 0);
      }
    }
  }
#pragma unroll
  for (int ct = 0; ct < 4; ++ct) {
    int c = c0 + ct * 16 + mr;
    if (c < VOCAB) {
      float bv = bmlp[c];
#pragma unroll
      for (int r = 0; r < 4; ++r) {
        int n = w * 16 + kg * 4 + r;
        out[n * VOCAB + c] = acc[ct][r] + bv;
      }
    }
  }
}

extern "C" void kernel_launch(void* const* d_in, const int* in_sizes, int n_in,
                              void* d_out, int out_size, void* d_ws, size_t ws_size,
                              hipStream_t stream) {
  const float* x     = (const float*)d_in[0];
  const float* hid   = (const float*)d_in[1];
  const float* cells = (const float*)d_in[2];
  const float* V     = (const float*)d_in[3];
  const float* Wsx   = (const float*)d_in[4];
  const float* Wsh   = (const float*)d_in[5];
  const float* Wv    = (const float*)d_in[6];
  const float* Wg    = (const float*)d_in[7];
  const float* Ws_   = (const float*)d_in[8];
  const float* Wh    = (const float*)d_in[9];
  const float* Wfeat = (const float*)d_in[10];
  const float* Wcxt  = (const float*)d_in[11];
  const float* Wg2   = (const float*)d_in[12];
  const float* Wspat = (const float*)d_in[13];
  const float* Wchan = (const float*)d_in[14];
  const float* Wgvs  = (const float*)d_in[15];
  const float* Wgvc  = (const float*)d_in[16];
  const float* Wghs  = (const float*)d_in[17];
  const float* Wghc  = (const float*)d_in[18];
  const float* Wmlp  = (const float*)d_in[19];
  const float* bmlp  = (const float*)d_in[20];
  float* ws  = (float*)d_ws;
  float* out = (float*)d_out;

  hipLaunchKernelGGL(k_sg2, dim3(448), dim3(256), 0, stream, Wsx, Wsh, Wg2, x, hid, V, ws);
  hipLaunchKernelGGL(k_act_s, dim3(128), dim3(256), 0, stream, cells, ws);
  hipLaunchKernelGGL(k_mid, dim3(896), dim3(256), 0, stream, Wfeat, Wcxt, Wgvs, Wghs, Wgvc, Wghc, hid, Wg, Ws_, ws);
  hipLaunchKernelGGL(k_attnM, dim3(1024), dim3(256), 0, stream, V, Wv, ws);
  hipLaunchKernelGGL(k_redM, dim3(10, 64), dim3(256), 0, stream, ws);
  hipLaunchKernelGGL(k_zt, dim3(64), dim3(256), 0, stream, Wh, ws, out);
  hipLaunchKernelGGL(k_cspat, dim3(2, 8, 16), dim3(256), 0, stream, V, Wspat, out, ws);
  hipLaunchKernelGGL(k_chat, dim3(2, 64), dim3(256), 0, stream, hid, Wchan, ws);
  hipLaunchKernelGGL(k_gemm_scores, dim3(157), dim3(256), 0, stream, Wmlp, bmlp, ws, out);
}

// Round 13
// 217.508 us; speedup vs baseline: 1.1307x; 1.1307x over previous
//
#include <hip/hip_runtime.h>

#define H 512
#define NTOK 64
#define NPIX 49
#define CDIM 2048
#define VOCAB 10000

// ws layout (float offsets). NO region requires zero-init (all plain-stored).
#define WS_S      0         // 64x512
#define WS_FM     163840    // 8x2048
#define WS_G2F    180224    // 64x512 reduced G2
#define WS_P1     212992    // 8 kc x 64 n x 64  (h@Wg partials)
#define WS_P2     245760    // 8 kc x 64 n x 64  (s@Ws partials)
#define WS_CCH    278528    // 16 kc x 64 n x 52 (cchan partials)
#define WS_A0     331776    // 64x2048 RAW cxt; CHT bf16 alias after death
#define WS_CHT    331776    // chat bf16 [n][512] (shorts)
// disjoint slab regions (ws is ~268MB; no time-sharing needed)
#define WS_SG2S   462848    // 48 x 32768  sg2 slabs (st*16+kc)
#define WS_GSPS   2035712   // 64 x 32768  gates+spat slabs (st*8+kc)
#define WS_MS     4132864   // 16 x 153664 M partial slabs
#define WS_SCS    6591488   // 4 x 640000  score slabs
#define WS_MF     9151488   // 64 x 2401 reduced M
// end = 9305152 floats ~= 37.2 MB

#define OUT_ALPHA 640000
#define OUT_BETA  643136

typedef __attribute__((ext_vector_type(8))) short short8;
typedef __attribute__((ext_vector_type(4))) float floatx4;

__device__ __forceinline__ float rcp_fast(float x) {
#if __has_builtin(__builtin_amdgcn_rcpf)
  return __builtin_amdgcn_rcpf(x);
#else
  return 1.0f / x;
#endif
}
__device__ __forceinline__ float tanh_f(float x) {
  float e = __expf(2.0f * x);
  return 1.0f - 2.0f * rcp_fast(e + 1.0f);
}
__device__ __forceinline__ float sigmoid_f(float x) {
  return rcp_fast(1.0f + __expf(-x));
}
__device__ __forceinline__ short f2bf(float x) {  // RNE fp32->bf16
  union { float f; unsigned u; } un; un.f = x;
  unsigned r = un.u + 0x7FFFu + ((un.u >> 16) & 1u);
  return (short)(r >> 16);
}
__device__ __forceinline__ float bf2f(unsigned short h) {
  union { unsigned u; float f; } cv; cv.u = ((unsigned)h) << 16;
  return cv.f;
}

// sg2 + featmean. bid<384: gemm streams 0:(x,Wsx) 1:(hprev,Wsh) 2:(h,Wg2)
// with self-staged A chunk; bid>=384: featmean.
__global__ __launch_bounds__(256) void k_sg2(const float* __restrict__ Wsx,
    const float* __restrict__ Wsh, const float* __restrict__ Wg2,
    const float* __restrict__ x, const float* __restrict__ hid,
    const float* __restrict__ V, float* __restrict__ ws) {
  int bid = blockIdx.x, tid = threadIdx.x;
  if (bid < 384) {
    __shared__ float aT[32 * 20];
    int c2 = bid & 1, kc = (bid >> 1) & 15, z = bid >> 5;   // z 0..11
    int st = z >> 2, n0 = (z & 3) * 16;
    int c = c2 * 256 + tid;
    int k0 = kc * 32;
    const float* W = (st == 0) ? Wsx : (st == 1) ? Wsh : Wg2;
    for (int i = tid; i < 512; i += 256) {
      int nn = i >> 5, kk = i & 31;
      int tok = n0 + nn;
      float v;
      if (st == 0)      v = x[tok * 512 + k0 + kk];
      else if (st == 1) v = (tok & 7) ? hid[(tok - 1) * 512 + k0 + kk] : 0.0f;
      else              v = hid[tok * 512 + k0 + kk];
      aT[kk * 20 + nn] = v;
    }
    __syncthreads();
    float acc[16];
#pragma unroll
    for (int j = 0; j < 16; ++j) acc[j] = 0.0f;
#pragma unroll 4
    for (int kk = 0; kk < 32; ++kk) {
      float w = W[(k0 + kk) * 512 + c];
      const float4* a4 = (const float4*)&aT[kk * 20];
#pragma unroll
      for (int q = 0; q < 4; ++q) {
        float4 a = a4[q];
        acc[q * 4 + 0] += a.x * w;
        acc[q * 4 + 1] += a.y * w;
        acc[q * 4 + 2] += a.z * w;
        acc[q * 4 + 3] += a.w * w;
      }
    }
    float* C = ws + WS_SG2S + (st * 16 + kc) * 32768;
#pragma unroll
    for (int j = 0; j < 16; ++j) C[(n0 + j) * 512 + c] = acc[j];
  } else {
    int fb = bid - 384;
    int b = fb >> 3, c = (fb & 7) * 256 + tid;
    float s = 0.0f;
    for (int k = 0; k < NPIX; ++k) s += V[b * NPIX * CDIM + k * CDIM + c];
    ws[WS_FM + b * CDIM + c] = s * (1.0f / NPIX);
  }
}

// reduce slabs: S = sigmoid(sum slabs 0..31)*tanh(cells) -> S ; G2F = sum slabs 32..47
__global__ __launch_bounds__(256) void k_act_s(const float* __restrict__ cells,
    float* __restrict__ ws) {
  int idx = blockIdx.x * 256 + threadIdx.x;
  float sa = 0.0f, g = 0.0f;
#pragma unroll
  for (int s = 0; s < 32; ++s) sa += ws[WS_SG2S + s * 32768 + idx];
#pragma unroll
  for (int s = 32; s < 48; ++s) g += ws[WS_SG2S + s * 32768 + idx];
  ws[WS_S + idx] = sigmoid_f(sa) * tanh_f(cells[idx]);
  ws[WS_G2F + idx] = g;
}

// bid<512: cxt raw ; 512<=bid<768: gates GEMMs (self-staged) ; bid>=768: cs_hwg
__global__ __launch_bounds__(256) void k_mid(const float* __restrict__ Wfeat,
    const float* __restrict__ Wcxt, const float* __restrict__ Wgvs,
    const float* __restrict__ Wghs, const float* __restrict__ Wgvc,
    const float* __restrict__ Wghc, const float* __restrict__ hid,
    const float* __restrict__ Wg, const float* __restrict__ Ws_,
    float* __restrict__ ws) {
  int bid = blockIdx.x, tid = threadIdx.x;
  if (bid < 512) {
    __shared__ float2 fw[512];
    __shared__ float g2l[512];
    int n = bid & 63, b = n >> 3;
    int c = (bid >> 6) * 256 + tid;
    for (int i = tid; i < 512; i += 256) {
      fw[i] = make_float2(Wfeat[i], Wcxt[i]);
      g2l[i] = ws[WS_G2F + n * H + i];
    }
    __syncthreads();
    float fm = ws[WS_FM + b * CDIM + c];
    float acc = 0.0f;
#pragma unroll 4
    for (int j = 0; j < 512; ++j) {
      float2 p = fw[j];
      acc += tanh_f(fm * p.x + g2l[j]) * p.y;
    }
    ws[WS_A0 + n * CDIM + c] = acc;
  } else if (bid < 768) {
    __shared__ float aT[64 * 20];
    int gi = bid - 512;                 // 0..255
    int c = (gi & 1) * 256 + tid;
    int rest = gi >> 1;                 // 0..127
    int kc = rest & 7;
    int zz = rest >> 3;                 // 0..15
    int st = zz >> 2, n0 = (zz & 3) * 16;
    int k0 = kc * 64;
    const float* Asrc = (st & 1) ? hid : (ws + WS_S);
    const float* W = (st == 0) ? Wgvs : (st == 1) ? Wghs : (st == 2) ? Wgvc : Wghc;
    for (int i = tid; i < 1024; i += 256) {
      int nn = i >> 6, kk = i & 63;
      aT[kk * 20 + nn] = Asrc[(n0 + nn) * 512 + k0 + kk];
    }
    __syncthreads();
    float acc[16];
#pragma unroll
    for (int j = 0; j < 16; ++j) acc[j] = 0.0f;
#pragma unroll 4
    for (int kk = 0; kk < 64; ++kk) {
      float w = W[(k0 + kk) * 512 + c];
      const float4* a4 = (const float4*)&aT[kk * 20];
#pragma unroll
      for (int q = 0; q < 4; ++q) {
        float4 a = a4[q];
        acc[q * 4 + 0] += a.x * w;
        acc[q * 4 + 1] += a.y * w;
        acc[q * 4 + 2] += a.z * w;
        acc[q * 4 + 3] += a.w * w;
      }
    }
    float* C = ws + WS_GSPS + (st * 8 + kc) * 32768;
#pragma unroll
    for (int j = 0; j < 16; ++j) C[(n0 + j) * 512 + c] = acc[j];
  } else {
    int bidx = bid - 768;               // 0..127
    int n = bidx & 63, half = bidx >> 6;
    int k2 = tid & 63, w = tid >> 6;
    int kc = half * 4 + w;
    const float* hrow = hid + n * H;
    const float* srow = ws + WS_S + n * H;
    float a1 = 0.0f, a2 = 0.0f;
#pragma unroll 4
    for (int kk = 0; kk < 64; ++kk) {
      int k = kc * 64 + kk;
      if (k2 < NPIX) {
        a1 += hrow[k] * Wg[k * NPIX + k2];
        a2 += srow[k] * Ws_[k * NPIX + k2];
      }
    }
    if (k2 < NPIX) {
      ws[WS_P1 + (kc * 64 + n) * 64 + k2] = a1;
      ws[WS_P2 + (kc * 64 + n) * 64 + k2] = a2;
    }
  }
}

// attnM via bf16 MFMA, softmax fused. grid 1024 = (16 kc)x(64 n).
__global__ __launch_bounds__(256) void k_attnM(const float* __restrict__ V,
    const float* __restrict__ Wv, float* __restrict__ ws) {
  __shared__ __align__(16) short al[64 * 136];
  __shared__ __align__(16) short bl[64 * 136];
  __shared__ float red[8];
  int tid = threadIdx.x, bid = blockIdx.x;
  int kc = bid >> 6, n = bid & 63, b = n >> 3;
  int c0 = kc * 128;
  const float* cr = ws + WS_A0 + n * CDIM;
  const float* Vb = V + b * NPIX * CDIM + c0;
  int lane = tid & 63, w = tid >> 6;
  float v[8];
  float vmax = -1e30f;
#pragma unroll
  for (int i = 0; i < 8; ++i) { v[i] = cr[tid + i * 256]; vmax = fmaxf(vmax, v[i]); }
  for (int off = 32; off; off >>= 1) vmax = fmaxf(vmax, __shfl_xor(vmax, off));
  if (lane == 0) red[w] = vmax;
  __syncthreads();
  float m = fmaxf(fmaxf(red[0], red[1]), fmaxf(red[2], red[3]));
  float ss = 0.0f;
#pragma unroll
  for (int i = 0; i < 8; ++i) ss += __expf(v[i] - m);
  for (int off = 32; off; off >>= 1) ss += __shfl_xor(ss, off);
  if (lane == 0) red[4 + w] = ss;
  __syncthreads();
  float inv = rcp_fast(red[4] + red[5] + red[6] + red[7]);
  {
    int cc = tid & 127;
    float a0c = __expf(cr[c0 + cc] - m) * inv;
    for (int k = tid >> 7; k < NPIX; k += 2)
      al[k * 136 + cc] = f2bf(a0c * Vb[k * CDIM + cc]);
  }
  for (int idx = tid; idx < 128 * 64; idx += 256) {
    int cc = idx >> 6, r = idx & 63;
    if (r < NPIX) bl[r * 136 + cc] = f2bf(Wv[(c0 + cc) * NPIX + r]);
  }
  __syncthreads();
  if (tid < NPIX) {
    float cch = 0.0f;
    const unsigned short* ar = (const unsigned short*)(al + tid * 136);
#pragma unroll 8
    for (int cc = 0; cc < 128; ++cc) cch += bf2f(ar[cc]);
    ws[WS_CCH + (kc * 64 + n) * 52 + tid] = cch * (1.0f / CDIM);
  }
  int qm = lane >> 4, mr = lane & 15;
  floatx4 acc[4];
#pragma unroll
  for (int i = 0; i < 4; ++i) acc[i] = (floatx4){0.f, 0.f, 0.f, 0.f};
#pragma unroll
  for (int ks = 0; ks < 4; ++ks) {
    int cb = ks * 32 + qm * 8;
    short8 bf = *(const short8*)&bl[(w * 16 + mr) * 136 + cb];
#pragma unroll
    for (int i = 0; i < 4; ++i) {
      short8 af = *(const short8*)&al[(i * 16 + mr) * 136 + cb];
      acc[i] = __builtin_amdgcn_mfma_f32_16x16x32_bf16(af, bf, acc[i], 0, 0, 0);
    }
  }
  __syncthreads();
  float* ml = (float*)al;
  int k2 = w * 16 + mr;
  if (k2 < NPIX) {
#pragma unroll
    for (int i = 0; i < 4; ++i) {
#pragma unroll
      for (int r = 0; r < 4; ++r) {
        int kp = i * 16 + qm * 4 + r;
        if (kp < NPIX) ml[k2 * 49 + kp] = acc[i][r];
      }
    }
  }
  __syncthreads();
  float* Mp = ws + WS_MS + kc * 153664 + n * 2401;
  for (int idx = tid; idx < 2401; idx += 256) Mp[idx] = ml[idx];
}

// reduce the 16 M slabs -> MF[n][2401] ; grid (10, 64)
__global__ __launch_bounds__(256) void k_redM(float* __restrict__ ws) {
  int n = blockIdx.y;
  int i = blockIdx.x * 256 + threadIdx.x;
  if (i < 2401) {
    float m = 0.0f;
#pragma unroll
    for (int s = 0; s < 16; ++s) m += ws[WS_MS + s * 153664 + n * 2401 + i];
    ws[WS_MF + n * 2401 + i] = m;
  }
}

// zt: reduce P1/P2; z from single MF slab; alpha, beta
__global__ __launch_bounds__(256) void k_zt(const float* __restrict__ Wh,
    float* __restrict__ ws, float* __restrict__ out) {
  __shared__ float gl[NPIX], cl[NPIX], whl[64];
  __shared__ float zbuf[4][64];
  int n = blockIdx.x, tid = threadIdx.x;
  if (tid < NPIX) {
    float s1 = 0.0f, s2 = 0.0f;
#pragma unroll
    for (int kc = 0; kc < 8; ++kc) {
      s1 += ws[WS_P1 + (kc * 64 + n) * 64 + tid];
      s2 += ws[WS_P2 + (kc * 64 + n) * 64 + tid];
    }
    gl[tid] = s1;
    cl[tid] = s1 + s2;
    whl[tid] = Wh[tid];
  }
  __syncthreads();
  int k = tid & 63, g = tid >> 6;
  float zp = 0.0f;
  if (k < NPIX) {
    int k2e = (g == 3) ? NPIX : (g * 13 + 13);
    const float* Mz = ws + WS_MF + n * 2401;
    for (int k2 = g * 13; k2 < k2e; ++k2) {
      float m = Mz[k2 * 49 + k];
      zp += tanh_f(tanh_f(m + gl[k2])) * whl[k2];
    }
  }
  zbuf[g][k] = zp;
  __syncthreads();
  if (tid < 64) {
    int lane = tid;
    float z = zbuf[0][lane] + zbuf[1][lane] + zbuf[2][lane] + zbuf[3][lane];
    float zm = (lane < NPIX) ? z : -1e30f;
    float m1 = zm;
    for (int off = 32; off; off >>= 1) m1 = fmaxf(m1, __shfl_xor(m1, off));
    float e = (lane < NPIX) ? __expf(z - m1) : 0.0f;
    float S1 = e;
    for (int off = 32; off; off >>= 1) S1 += __shfl_xor(S1, off);
    if (lane < NPIX) out[OUT_ALPHA + n * NPIX + lane] = e * rcp_fast(S1);
    float vz = (lane < NPIX) ? tanh_f(cl[lane]) * whl[lane] : 0.0f;
    for (int off = 32; off; off >>= 1) vz += __shfl_xor(vz, off);
    if (lane == 0) {
      float ze = vz;
      float m2 = fmaxf(m1, ze);
      float S2 = S1 * __expf(m1 - m2) + __expf(ze - m2);
      out[OUT_BETA + n] = __expf(ze - m2) * rcp_fast(S2);
    }
  }
}

// FUSED c_spatial + spat gemm. grid (2 c2, 8 kc, 16 z={q*4+n0g}).
__global__ __launch_bounds__(256) void k_cspat(const float* __restrict__ V,
    const float* __restrict__ Wspat, const float* __restrict__ out,
    float* __restrict__ ws) {
  __shared__ float vs[2 * 49 * 64];   // 25 KB
  __shared__ float alp[16 * 64];      // 4 KB
  __shared__ float aT[64 * 20];       // 5 KB
  int tid = threadIdx.x;
  int c2 = blockIdx.x, kc = blockIdx.y, z = blockIdx.z;
  int q = z >> 2, n0 = (z & 3) * 16;
  int d0 = q * 512 + kc * 64;
  int b0 = n0 >> 3;                   // spans batches b0, b0+1
  for (int i = tid; i < 2 * 49 * 64; i += 256) {
    int d = i & 63, t = i >> 6;       // t 0..97
    int bb = (t >= 49) ? 1 : 0;
    int kp = t - bb * 49;
    vs[i] = V[(b0 + bb) * NPIX * CDIM + kp * CDIM + d0 + d];
  }
  for (int i = tid; i < 1024; i += 256) {
    int nl = i >> 6, kp = i & 63;
    alp[i] = (kp < NPIX) ? out[OUT_ALPHA + (n0 + nl) * NPIX + kp] : 0.0f;
  }
  __syncthreads();
  {
    int d = tid & 63, ng = tid >> 6;  // ng wave-uniform
    int bb = ng >> 1;
    float a0 = 0.f, a1 = 0.f, a2 = 0.f, a3 = 0.f;
#pragma unroll 7
    for (int kp = 0; kp < NPIX; ++kp) {
      float v = vs[(bb * 49 + kp) * 64 + d];
      a0 += alp[(ng * 4 + 0) * 64 + kp] * v;
      a1 += alp[(ng * 4 + 1) * 64 + kp] * v;
      a2 += alp[(ng * 4 + 2) * 64 + kp] * v;
      a3 += alp[(ng * 4 + 3) * 64 + kp] * v;
    }
    aT[d * 20 + ng * 4 + 0] = a0;
    aT[d * 20 + ng * 4 + 1] = a1;
    aT[d * 20 + ng * 4 + 2] = a2;
    aT[d * 20 + ng * 4 + 3] = a3;
  }
  __syncthreads();
  int c = c2 * 256 + tid;
  float acc[16];
#pragma unroll
  for (int j = 0; j < 16; ++j) acc[j] = 0.0f;
#pragma unroll 4
  for (int kk = 0; kk < 64; ++kk) {
    float w = Wspat[(d0 + kk) * 512 + c];
    const float4* a4 = (const float4*)&aT[kk * 20];
#pragma unroll
    for (int q2 = 0; q2 < 4; ++q2) {
      float4 a = a4[q2];
      acc[q2 * 4 + 0] += a.x * w;
      acc[q2 * 4 + 1] += a.y * w;
      acc[q2 * 4 + 2] += a.z * w;
      acc[q2 * 4 + 3] += a.w * w;
    }
  }
  float* C = ws + WS_GSPS + ((4 + q) * 8 + kc) * 32768;
#pragma unroll
  for (int j = 0; j < 16; ++j) C[(n0 + j) * 512 + c] = acc[j];
}

// chat[n][c] = sigmoid(GA1)*SPAT + sigmoid(GA2)*(cchan@Wchan) + h -> bf16 [n][512]
__global__ __launch_bounds__(256) void k_chat(const float* __restrict__ hid,
    const float* __restrict__ Wchan, float* __restrict__ ws) {
  __shared__ float cl[NPIX];
  int tid = threadIdx.x, n = blockIdx.y;
  int c = blockIdx.x * 256 + tid;
  if (tid < NPIX) {
    float s = 0.0f;
#pragma unroll
    for (int kc = 0; kc < 16; ++kc) s += ws[WS_CCH + (kc * 64 + n) * 52 + tid];
    cl[tid] = s;
  }
  __syncthreads();
  float acc = 0.0f;
#pragma unroll 7
  for (int k = 0; k < NPIX; ++k) acc += cl[k] * Wchan[k * H + c];
  int idx = n * H + c;
  float ga1 = 0.0f, ga2 = 0.0f, spat = 0.0f;
#pragma unroll
  for (int s = 0; s < 16; ++s)  ga1 += ws[WS_GSPS + s * 32768 + idx];
#pragma unroll
  for (int s = 16; s < 32; ++s) ga2 += ws[WS_GSPS + s * 32768 + idx];
#pragma unroll
  for (int s = 32; s < 64; ++s) spat += ws[WS_GSPS + s * 32768 + idx];
  float chat = sigmoid_f(ga1) * spat + sigmoid_f(ga2) * acc + hid[idx];
  ((short*)(ws + WS_CHT))[idx] = f2bf(chat);
}

// scores via bf16 MFMA: grid (157 cb, 4 kc) -> 4 partial slabs.
// B staged LDS bf16 [c][k]; A fragments from global CHB (L2-hot 64KB).
__global__ __launch_bounds__(256) void k_gemm_scores(const float* __restrict__ Wmlp,
    float* __restrict__ ws) {
  __shared__ __align__(16) short bl[64 * 136];
  int tid = threadIdx.x;
  int cb = blockIdx.x, kc = blockIdx.y;
  int c0 = cb * 64, k0 = kc * 128;
  const short* CHB = (const short*)(ws + WS_CHT);
  int lane = tid & 63, w = tid >> 6;
  int mr = lane & 15, kg = lane >> 4;
  for (int i = tid; i < 128 * 64; i += 256) {
    int kk = i >> 6, cc = i & 63;
    int c = c0 + cc;
    float v = (c < VOCAB) ? Wmlp[(k0 + kk) * VOCAB + c] : 0.0f;
    bl[cc * 136 + kk] = f2bf(v);
  }
  __syncthreads();
  floatx4 acc[4];
#pragma unroll
  for (int i = 0; i < 4; ++i) acc[i] = (floatx4){0.f, 0.f, 0.f, 0.f};
#pragma unroll
  for (int ks = 0; ks < 4; ++ks) {
    short8 af = *(const short8*)&CHB[(w * 16 + mr) * 512 + k0 + ks * 32 + kg * 8];
#pragma unroll
    for (int ct = 0; ct < 4; ++ct) {
      short8 bf = *(const short8*)&bl[(ct * 16 + mr) * 136 + ks * 32 + kg * 8];
      acc[ct] = __builtin_amdgcn_mfma_f32_16x16x32_bf16(af, bf, acc[ct], 0, 0, 0);
    }
  }
  float* slab = ws + WS_SCS + kc * 640000;
#pragma unroll
  for (int ct = 0; ct < 4; ++ct) {
    int c = c0 + ct * 16 + mr;
    if (c < VOCAB) {
#pragma unroll
      for (int r = 0; r < 4; ++r) {
        int n = w * 16 + kg * 4 + r;
        slab[n * VOCAB + c] = acc[ct][r];
      }
    }
  }
}

// out[n][c] = bmlp[c] + sum of 4 score slabs ; float4 ; grid (10, 64)
__global__ __launch_bounds__(256) void k_red_scores(const float* __restrict__ bmlp,
    float* __restrict__ ws, float* __restrict__ out) {
  int c4 = blockIdx.x * 256 + threadIdx.x, n = blockIdx.y;
  if (c4 >= VOCAB / 4) return;
  const float4* b4 = (const float4*)bmlp;
  float4 v = b4[c4];
#pragma unroll
  for (int s = 0; s < 4; ++s) {
    float4 p = ((const float4*)(ws + WS_SCS + s * 640000 + n * VOCAB))[c4];
    v.x += p.x; v.y += p.y; v.z += p.z; v.w += p.w;
  }
  ((float4*)(out + n * VOCAB))[c4] = v;
}

extern "C" void kernel_launch(void* const* d_in, const int* in_sizes, int n_in,
                              void* d_out, int out_size, void* d_ws, size_t ws_size,
                              hipStream_t stream) {
  const float* x     = (const float*)d_in[0];
  const float* hid   = (const float*)d_in[1];
  const float* cells = (const float*)d_in[2];
  const float* V     = (const float*)d_in[3];
  const float* Wsx   = (const float*)d_in[4];
  const float* Wsh   = (const float*)d_in[5];
  const float* Wv    = (const float*)d_in[6];
  const float* Wg    = (const float*)d_in[7];
  const float* Ws_   = (const float*)d_in[8];
  const float* Wh    = (const float*)d_in[9];
  const float* Wfeat = (const float*)d_in[10];
  const float* Wcxt  = (const float*)d_in[11];
  const float* Wg2   = (const float*)d_in[12];
  const float* Wspat = (const float*)d_in[13];
  const float* Wchan = (const float*)d_in[14];
  const float* Wgvs  = (const float*)d_in[15];
  const float* Wgvc  = (const float*)d_in[16];
  const float* Wghs  = (const float*)d_in[17];
  const float* Wghc  = (const float*)d_in[18];
  const float* Wmlp  = (const float*)d_in[19];
  const float* bmlp  = (const float*)d_in[20];
  float* ws  = (float*)d_ws;
  float* out = (float*)d_out;

  hipLaunchKernelGGL(k_sg2, dim3(448), dim3(256), 0, stream, Wsx, Wsh, Wg2, x, hid, V, ws);
  hipLaunchKernelGGL(k_act_s, dim3(128), dim3(256), 0, stream, cells, ws);
  hipLaunchKernelGGL(k_mid, dim3(896), dim3(256), 0, stream, Wfeat, Wcxt, Wgvs, Wghs, Wgvc, Wghc, hid, Wg, Ws_, ws);
  hipLaunchKernelGGL(k_attnM, dim3(1024), dim3(256), 0, stream, V, Wv, ws);
  hipLaunchKernelGGL(k_redM, dim3(10, 64), dim3(256), 0, stream, ws);
  hipLaunchKernelGGL(k_zt, dim3(64), dim3(256), 0, stream, Wh, ws, out);
  hipLaunchKernelGGL(k_cspat, dim3(2, 8, 16), dim3(256), 0, stream, V, Wspat, out, ws);
  hipLaunchKernelGGL(k_chat, dim3(2, 64), dim3(256), 0, stream, hid, Wchan, ws);
  hipLaunchKernelGGL(k_gemm_scores, dim3(157, 4), dim3(256), 0, stream, Wmlp, ws);
  hipLaunchKernelGGL(k_red_scores, dim3(10, 64), dim3(256), 0, stream, bmlp, ws, out);
}